// Round 1
// baseline (1259.468 us; speedup 1.0000x reference)
//
#include <hip/hip_runtime.h>
#include <hip/hip_bf16.h>

#define BATCH 16
#define HW 50176          // 224*224
#define HID 256
#define K 64
#define PIX_BLOCKS_PER_IMG 196   // 50176 / 256

// output layout (floats): transformed [0, 2408448) | m [2408448, 53788672) | palette [53788672, +3072)
#define OUT_T_OFF 0
#define OUT_M_OFF 2408448
#define OUT_P_OFF 53788672

// Kernel A: per-pixel MLP (3->256 relu -> 64) + softmax over K, write m.
__global__ __launch_bounds__(256) void colorcnn_mlp_softmax(
    const float* __restrict__ img, const float* __restrict__ W1,
    const float* __restrict__ b1, const float* __restrict__ W2,
    float* __restrict__ m_out)
{
    const int b = blockIdx.x / PIX_BLOCKS_PER_IMG;
    const int p = (blockIdx.x % PIX_BLOCKS_PER_IMG) * 256 + threadIdx.x;

    const float* ip = img + (size_t)b * 3 * HW + p;
    const float r  = ip[0];
    const float g  = ip[HW];
    const float bl = ip[2 * HW];

    float acc[K];
#pragma unroll
    for (int k = 0; k < K; ++k) acc[k] = 0.f;

    for (int o = 0; o < HID; ++o) {
        float t = fmaf(r, W1[o * 3 + 0],
                  fmaf(g, W1[o * 3 + 1],
                  fmaf(bl, W1[o * 3 + 2], b1[o])));
        t = fmaxf(t, 0.f);
#pragma unroll
        for (int k = 0; k < K; ++k)
            acc[k] = fmaf(t, W2[k * HID + o], acc[k]);
    }

    // softmax over K
    float mx = acc[0];
#pragma unroll
    for (int k = 1; k < K; ++k) mx = fmaxf(mx, acc[k]);
    float s = 0.f;
#pragma unroll
    for (int k = 0; k < K; ++k) { acc[k] = __expf(acc[k] - mx); s += acc[k]; }
    const float inv = 1.f / s;

    float* mo = m_out + (size_t)b * K * HW + p;
#pragma unroll
    for (int k = 0; k < K; ++k) mo[(size_t)k * HW] = acc[k] * inv;
}

// Kernel B: one block per (b,k): den[b,k] = sum_p m ; num[b,c,k] = sum_p img_c * m
__global__ __launch_bounds__(256) void colorcnn_reduce(
    const float* __restrict__ img, const float* __restrict__ m,
    float* __restrict__ den_ws, float* __restrict__ num_ws)
{
    const int b = blockIdx.x >> 6;
    const int k = blockIdx.x & 63;
    const float* mp = m + ((size_t)b * K + k) * HW;
    const float* ip = img + (size_t)b * 3 * HW;

    float d = 0.f, nr = 0.f, ng = 0.f, nb = 0.f;
    for (int p = threadIdx.x; p < HW; p += 256) {
        const float mv = mp[p];
        d  += mv;
        nr  = fmaf(ip[p],          mv, nr);
        ng  = fmaf(ip[HW + p],     mv, ng);
        nb  = fmaf(ip[2 * HW + p], mv, nb);
    }
    // wave(64) butterfly reduce
#pragma unroll
    for (int off = 32; off >= 1; off >>= 1) {
        d  += __shfl_down(d,  off);
        nr += __shfl_down(nr, off);
        ng += __shfl_down(ng, off);
        nb += __shfl_down(nb, off);
    }
    __shared__ float sred[4][4];
    const int wave = threadIdx.x >> 6;
    const int lane = threadIdx.x & 63;
    if (lane == 0) {
        sred[wave][0] = d; sred[wave][1] = nr; sred[wave][2] = ng; sred[wave][3] = nb;
    }
    __syncthreads();
    if (threadIdx.x == 0) {
        float D = sred[0][0] + sred[1][0] + sred[2][0] + sred[3][0];
        float R = sred[0][1] + sred[1][1] + sred[2][1] + sred[3][1];
        float G = sred[0][2] + sred[1][2] + sred[2][2] + sred[3][2];
        float Bv = sred[0][3] + sred[1][3] + sred[2][3] + sred[3][3];
        den_ws[b * K + k] = D;
        num_ws[(b * 3 + 0) * K + k] = R;
        num_ws[(b * 3 + 1) * K + k] = G;
        num_ws[(b * 3 + 2) * K + k] = Bv;
    }
}

// Kernel P: palette[b,c,k] = num/(den+eps)
__global__ __launch_bounds__(256) void colorcnn_palette(
    const float* __restrict__ den_ws, const float* __restrict__ num_ws,
    float* __restrict__ pal_out)
{
    const int i = blockIdx.x * 256 + threadIdx.x;   // i = b*64+k, i < 1024
    if (i >= BATCH * K) return;
    const int b = i >> 6;
    const int k = i & 63;
    const float dv = den_ws[i] + 1e-8f;
#pragma unroll
    for (int c = 0; c < 3; ++c)
        pal_out[b * 3 * K + c * K + k] = num_ws[(b * 3 + c) * K + k] / dv;
}

// Kernel C: transformed[b,c,p] = sum_k m[b,k,p] * palette[b,c,k]
__global__ __launch_bounds__(256) void colorcnn_reconstruct(
    const float* __restrict__ m, const float* __restrict__ pal,
    float* __restrict__ t_out)
{
    const int b = blockIdx.x / PIX_BLOCKS_PER_IMG;
    const int p = (blockIdx.x % PIX_BLOCKS_PER_IMG) * 256 + threadIdx.x;

    const float* mp = m + (size_t)b * K * HW + p;
    const float* pb = pal + b * 3 * K;

    float ar = 0.f, ag = 0.f, ab = 0.f;
#pragma unroll
    for (int k = 0; k < K; ++k) {
        const float mv = mp[(size_t)k * HW];
        ar = fmaf(mv, pb[k],           ar);
        ag = fmaf(mv, pb[K + k],       ag);
        ab = fmaf(mv, pb[2 * K + k],   ab);
    }
    float* to = t_out + (size_t)b * 3 * HW + p;
    to[0]      = ar;
    to[HW]     = ag;
    to[2 * HW] = ab;
}

extern "C" void kernel_launch(void* const* d_in, const int* in_sizes, int n_in,
                              void* d_out, int out_size, void* d_ws, size_t ws_size,
                              hipStream_t stream) {
    const float* img = (const float*)d_in[0];
    const float* W1  = (const float*)d_in[1];
    const float* b1  = (const float*)d_in[2];
    const float* W2  = (const float*)d_in[3];

    float* out   = (float*)d_out;
    float* t_out = out + OUT_T_OFF;
    float* m_out = out + OUT_M_OFF;
    float* p_out = out + OUT_P_OFF;

    float* den_ws = (float*)d_ws;                  // BATCH*K floats
    float* num_ws = den_ws + BATCH * K;            // BATCH*3*K floats

    const int pix_blocks = BATCH * PIX_BLOCKS_PER_IMG;   // 3136

    colorcnn_mlp_softmax<<<pix_blocks, 256, 0, stream>>>(img, W1, b1, W2, m_out);
    colorcnn_reduce<<<BATCH * K, 256, 0, stream>>>(img, m_out, den_ws, num_ws);
    colorcnn_palette<<<4, 256, 0, stream>>>(den_ws, num_ws, p_out);
    colorcnn_reconstruct<<<pix_blocks, 256, 0, stream>>>(m_out, p_out, t_out);
}

// Round 2
// 631.573 us; speedup vs baseline: 1.9942x; 1.9942x over previous
//
#include <hip/hip_runtime.h>
#include <hip/hip_bf16.h>

#define BATCH 16
#define HW 50176          // 224*224
#define HID 256
#define K 64
#define PIX_PER_BLOCK 512            // 2 pixels per thread, 256 threads
#define PIX_BLOCKS_PER_IMG 98        // 50176 / 512
#define REC_BLOCKS_PER_IMG 196       // 50176 / 256

// output layout (floats): transformed [0, 2408448) | m [2408448, 53788672) | palette [53788672, +3072)
#define OUT_T_OFF 0
#define OUT_M_OFF 2408448
#define OUT_P_OFF 53788672

// Kernel A: per-pixel MLP (3->256 relu -> 64) + softmax over K, write m.
// 2 pixels per thread; acc kept in VGPRs (launch_bounds(256,1) -> big reg budget).
__global__ __launch_bounds__(256, 1) void colorcnn_mlp_softmax(
    const float* __restrict__ img, const float* __restrict__ W1,
    const float* __restrict__ b1, const float* __restrict__ W2,
    float* __restrict__ m_out)
{
    const int b  = blockIdx.x / PIX_BLOCKS_PER_IMG;
    const int p0 = (blockIdx.x % PIX_BLOCKS_PER_IMG) * PIX_PER_BLOCK + threadIdx.x;
    const int p1 = p0 + 256;

    const float* ip = img + (size_t)b * 3 * HW;
    const float r0 = ip[p0], g0 = ip[HW + p0], u0 = ip[2 * HW + p0];
    const float r1 = ip[p1], g1 = ip[HW + p1], u1 = ip[2 * HW + p1];

    float acc0[K], acc1[K];
#pragma unroll
    for (int k = 0; k < K; ++k) { acc0[k] = 0.f; acc1[k] = 0.f; }

    for (int o = 0; o < HID; ++o) {
        const float w0 = W1[o * 3 + 0];
        const float w1 = W1[o * 3 + 1];
        const float w2 = W1[o * 3 + 2];
        const float bb = b1[o];
        float t0 = fmaf(r0, w0, fmaf(g0, w1, fmaf(u0, w2, bb)));
        float t1 = fmaf(r1, w0, fmaf(g1, w1, fmaf(u1, w2, bb)));
        t0 = fmaxf(t0, 0.f);
        t1 = fmaxf(t1, 0.f);
#pragma unroll
        for (int k = 0; k < K; ++k) {
            const float w = W2[k * HID + o];
            acc0[k] = fmaf(t0, w, acc0[k]);
            acc1[k] = fmaf(t1, w, acc1[k]);
        }
    }

    // softmax over K (each pixel independent)
    float mx0 = acc0[0], mx1 = acc1[0];
#pragma unroll
    for (int k = 1; k < K; ++k) { mx0 = fmaxf(mx0, acc0[k]); mx1 = fmaxf(mx1, acc1[k]); }
    float s0 = 0.f, s1 = 0.f;
#pragma unroll
    for (int k = 0; k < K; ++k) {
        acc0[k] = __expf(acc0[k] - mx0); s0 += acc0[k];
        acc1[k] = __expf(acc1[k] - mx1); s1 += acc1[k];
    }
    const float inv0 = 1.f / s0;
    const float inv1 = 1.f / s1;

    float* mo = m_out + (size_t)b * K * HW;
#pragma unroll
    for (int k = 0; k < K; ++k) {
        mo[(size_t)k * HW + p0] = acc0[k] * inv0;
        mo[(size_t)k * HW + p1] = acc1[k] * inv1;
    }
}

// Kernel B: one block per (b,k): den[b,k] = sum_p m ; num[b,c,k] = sum_p img_c * m
__global__ __launch_bounds__(256) void colorcnn_reduce(
    const float* __restrict__ img, const float* __restrict__ m,
    float* __restrict__ den_ws, float* __restrict__ num_ws)
{
    const int b = blockIdx.x >> 6;
    const int k = blockIdx.x & 63;
    const float* mp = m + ((size_t)b * K + k) * HW;
    const float* ip = img + (size_t)b * 3 * HW;

    float d = 0.f, nr = 0.f, ng = 0.f, nb = 0.f;
    for (int p = threadIdx.x; p < HW; p += 256) {
        const float mv = mp[p];
        d  += mv;
        nr  = fmaf(ip[p],          mv, nr);
        ng  = fmaf(ip[HW + p],     mv, ng);
        nb  = fmaf(ip[2 * HW + p], mv, nb);
    }
#pragma unroll
    for (int off = 32; off >= 1; off >>= 1) {
        d  += __shfl_down(d,  off);
        nr += __shfl_down(nr, off);
        ng += __shfl_down(ng, off);
        nb += __shfl_down(nb, off);
    }
    __shared__ float sred[4][4];
    const int wave = threadIdx.x >> 6;
    const int lane = threadIdx.x & 63;
    if (lane == 0) {
        sred[wave][0] = d; sred[wave][1] = nr; sred[wave][2] = ng; sred[wave][3] = nb;
    }
    __syncthreads();
    if (threadIdx.x == 0) {
        float D  = sred[0][0] + sred[1][0] + sred[2][0] + sred[3][0];
        float R  = sred[0][1] + sred[1][1] + sred[2][1] + sred[3][1];
        float G  = sred[0][2] + sred[1][2] + sred[2][2] + sred[3][2];
        float Bv = sred[0][3] + sred[1][3] + sred[2][3] + sred[3][3];
        den_ws[b * K + k] = D;
        num_ws[(b * 3 + 0) * K + k] = R;
        num_ws[(b * 3 + 1) * K + k] = G;
        num_ws[(b * 3 + 2) * K + k] = Bv;
    }
}

// Kernel P: palette[b,c,k] = num/(den+eps)
__global__ __launch_bounds__(256) void colorcnn_palette(
    const float* __restrict__ den_ws, const float* __restrict__ num_ws,
    float* __restrict__ pal_out)
{
    const int i = blockIdx.x * 256 + threadIdx.x;   // i = b*64+k, i < 1024
    if (i >= BATCH * K) return;
    const int b = i >> 6;
    const int k = i & 63;
    const float dv = den_ws[i] + 1e-8f;
#pragma unroll
    for (int c = 0; c < 3; ++c)
        pal_out[b * 3 * K + c * K + k] = num_ws[(b * 3 + c) * K + k] / dv;
}

// Kernel C: transformed[b,c,p] = sum_k m[b,k,p] * palette[b,c,k]
__global__ __launch_bounds__(256) void colorcnn_reconstruct(
    const float* __restrict__ m, const float* __restrict__ pal,
    float* __restrict__ t_out)
{
    const int b = blockIdx.x / REC_BLOCKS_PER_IMG;
    const int p = (blockIdx.x % REC_BLOCKS_PER_IMG) * 256 + threadIdx.x;

    const float* mp = m + (size_t)b * K * HW + p;
    const float* pb = pal + b * 3 * K;

    float ar = 0.f, ag = 0.f, ab = 0.f;
#pragma unroll
    for (int k = 0; k < K; ++k) {
        const float mv = mp[(size_t)k * HW];
        ar = fmaf(mv, pb[k],         ar);
        ag = fmaf(mv, pb[K + k],     ag);
        ab = fmaf(mv, pb[2 * K + k], ab);
    }
    float* to = t_out + (size_t)b * 3 * HW + p;
    to[0]      = ar;
    to[HW]     = ag;
    to[2 * HW] = ab;
}

extern "C" void kernel_launch(void* const* d_in, const int* in_sizes, int n_in,
                              void* d_out, int out_size, void* d_ws, size_t ws_size,
                              hipStream_t stream) {
    const float* img = (const float*)d_in[0];
    const float* W1  = (const float*)d_in[1];
    const float* b1  = (const float*)d_in[2];
    const float* W2  = (const float*)d_in[3];

    float* out   = (float*)d_out;
    float* t_out = out + OUT_T_OFF;
    float* m_out = out + OUT_M_OFF;
    float* p_out = out + OUT_P_OFF;

    float* den_ws = (float*)d_ws;                  // BATCH*K floats
    float* num_ws = den_ws + BATCH * K;            // BATCH*3*K floats

    colorcnn_mlp_softmax<<<BATCH * PIX_BLOCKS_PER_IMG, 256, 0, stream>>>(img, W1, b1, W2, m_out);
    colorcnn_reduce<<<BATCH * K, 256, 0, stream>>>(img, m_out, den_ws, num_ws);
    colorcnn_palette<<<4, 256, 0, stream>>>(den_ws, num_ws, p_out);
    colorcnn_reconstruct<<<BATCH * REC_BLOCKS_PER_IMG, 256, 0, stream>>>(m_out, p_out, t_out);
}

// Round 4
// 186.864 us; speedup vs baseline: 6.7400x; 3.3798x over previous
//
#include <hip/hip_runtime.h>
#include <hip/hip_bf16.h>

#define BATCH 16
#define HW 50176          // 224*224
#define HID 256
#define K 64
#define REC_BLOCKS_PER_IMG 196       // 50176 / 256

// output layout (floats): transformed [0, 2408448) | m [2408448, 53788672) | palette [53788672, +3072)
#define OUT_T_OFF 0
#define OUT_M_OFF 2408448
#define OUT_P_OFF 53788672

// workspace layout (floats): den [0,1024) | num [1024,4096) | w1p float4 [4096,5120) | w2b bf16 @ float-offset 5120 (32KB)
#define WS_DEN 0
#define WS_NUM 1024
#define WS_W1P 4096
#define WS_W2B 5120

typedef short bf16x8 __attribute__((ext_vector_type(8)));
typedef float f32x4  __attribute__((ext_vector_type(4)));

static __device__ __forceinline__ short f2bf(float x) {
    union { __hip_bfloat16 h; short s; } u;
    u.h = __float2bfloat16(x);
    return u.s;
}

// Prep: pack W1+b1 into float4[256]; convert W2 to bf16[64*256]. One block, 256 threads.
__global__ __launch_bounds__(256) void colorcnn_prep(
    const float* __restrict__ W1, const float* __restrict__ b1,
    const float* __restrict__ W2, float4* __restrict__ w1p,
    ushort* __restrict__ w2b)
{
    const int t = threadIdx.x;
    w1p[t] = make_float4(W1[3 * t], W1[3 * t + 1], W1[3 * t + 2], b1[t]);
#pragma unroll
    for (int q = 0; q < 64; ++q) {
        const int i = q * 256 + t;
        w2b[i] = (ushort)f2bf(W2[i]);
    }
}

// Kernel A: per-pixel MLP via MFMA + softmax, write m.
// Block = 128 consecutive pixels of image blockIdx.y; 4 waves x 32 px each.
__global__ __launch_bounds__(256) void colorcnn_mlp_softmax(
    const float* __restrict__ img, const float4* __restrict__ w1p,
    const ushort* __restrict__ w2b, float* __restrict__ m_out)
{
    __shared__ int4 lds[2304];   // [0,2048): w2b swizzled; [2048,2304): w1p swizzled

    const int t = threadIdx.x;
    // stage w2b: 2048 16B units; unit s of row n stored at n*32 + (s ^ (n&7))
    const int4* w2b16 = (const int4*)w2b;
#pragma unroll
    for (int q = 0; q < 8; ++q) {
        const int i = t + q * 256;
        const int n = i >> 5, s = i & 31;
        lds[n * 32 + (s ^ (n & 7))] = w2b16[i];
    }
    // stage w1p: unit hid stored at 2048 + (hid ^ ((hid>>3)&3))
    lds[2048 + (t ^ ((t >> 3) & 3))] = ((const int4*)w1p)[t];
    __syncthreads();

    const int b    = blockIdx.y;
    const int pb   = blockIdx.x * 128;
    const int w    = t >> 6;
    const int lane = t & 63;
    const int l15  = lane & 15;
    const int lg   = lane >> 4;

    const float* ip = img + (size_t)b * 3 * HW;
    const int px0 = pb + w * 32 + l15;
    const int px1 = px0 + 16;
    const float r0 = ip[px0], g0 = ip[HW + px0], u0 = ip[2 * HW + px0];
    const float r1 = ip[px1], g1 = ip[HW + px1], u1 = ip[2 * HW + px1];

    f32x4 acc[2][4];
#pragma unroll
    for (int mi = 0; mi < 2; ++mi)
#pragma unroll
        for (int ni = 0; ni < 4; ++ni)
            acc[mi][ni] = (f32x4){0.f, 0.f, 0.f, 0.f};

#pragma unroll
    for (int c = 0; c < 8; ++c) {
        // Build A fragments: lane holds h[px][hid], hid = c*32 + lg*8 + j
        bf16x8 a0, a1;
#pragma unroll
        for (int j = 0; j < 8; ++j) {
            const int hid = c * 32 + lg * 8 + j;
            const float4 wv = *(const float4*)&lds[2048 + (hid ^ lg)];
            float t0 = fmaf(r0, wv.x, fmaf(g0, wv.y, fmaf(u0, wv.z, wv.w)));
            float t1 = fmaf(r1, wv.x, fmaf(g1, wv.y, fmaf(u1, wv.z, wv.w)));
            a0[j] = f2bf(fmaxf(t0, 0.f));
            a1[j] = f2bf(fmaxf(t1, 0.f));
        }
        // B fragments from LDS (swizzled) + 8 MFMA
#pragma unroll
        for (int ni = 0; ni < 4; ++ni) {
            const int n = ni * 16 + l15;
            const bf16x8 bf = *(const bf16x8*)&lds[n * 32 + (((c * 4 + lg) ^ (n & 7)))];
            acc[0][ni] = __builtin_amdgcn_mfma_f32_16x16x32_bf16(a0, bf, acc[0][ni], 0, 0, 0);
            acc[1][ni] = __builtin_amdgcn_mfma_f32_16x16x32_bf16(a1, bf, acc[1][ni], 0, 0, 0);
        }
    }

    // Softmax over n (64 outputs) per pixel. C layout: col(n)=ni*16+l15, row(px)=mi*16+lg*4+reg.
    // Rows are identical across the 16 lanes sharing lg -> reduce over l15 via shfl_xor 1,2,4,8.
#pragma unroll
    for (int mi = 0; mi < 2; ++mi) {
#pragma unroll
        for (int reg = 0; reg < 4; ++reg) {
            float v0 = acc[mi][0][reg], v1 = acc[mi][1][reg];
            float v2 = acc[mi][2][reg], v3 = acc[mi][3][reg];
            float mx = fmaxf(fmaxf(v0, v1), fmaxf(v2, v3));
            mx = fmaxf(mx, __shfl_xor(mx, 1));
            mx = fmaxf(mx, __shfl_xor(mx, 2));
            mx = fmaxf(mx, __shfl_xor(mx, 4));
            mx = fmaxf(mx, __shfl_xor(mx, 8));
            v0 = __expf(v0 - mx); v1 = __expf(v1 - mx);
            v2 = __expf(v2 - mx); v3 = __expf(v3 - mx);
            float s = (v0 + v1) + (v2 + v3);
            s += __shfl_xor(s, 1);
            s += __shfl_xor(s, 2);
            s += __shfl_xor(s, 4);
            s += __shfl_xor(s, 8);
            const float inv = 1.f / s;
            acc[mi][0][reg] = v0 * inv; acc[mi][1][reg] = v1 * inv;
            acc[mi][2][reg] = v2 * inv; acc[mi][3][reg] = v3 * inv;
        }
    }

    // Store m: per (mi,ni) the 4 regs are 4 consecutive px -> dwordx4; 16 full 64B lines per instr.
    float* mo = m_out + (size_t)b * K * HW + pb + w * 32;
#pragma unroll
    for (int mi = 0; mi < 2; ++mi)
#pragma unroll
        for (int ni = 0; ni < 4; ++ni) {
            const int n = ni * 16 + l15;
            *(f32x4*)&mo[(size_t)n * HW + mi * 16 + lg * 4] = acc[mi][ni];
        }
}

// Kernel B: one block per (b,k): den[b,k] = sum_p m ; num[b,c,k] = sum_p img_c * m
__global__ __launch_bounds__(256) void colorcnn_reduce(
    const float* __restrict__ img, const float* __restrict__ m,
    float* __restrict__ den_ws, float* __restrict__ num_ws)
{
    const int b = blockIdx.x >> 6;
    const int k = blockIdx.x & 63;
    const float* mp = m + ((size_t)b * K + k) * HW;
    const float* ip = img + (size_t)b * 3 * HW;

    float d = 0.f, nr = 0.f, ng = 0.f, nb = 0.f;
    for (int p = threadIdx.x; p < HW; p += 256) {
        const float mv = mp[p];
        d  += mv;
        nr  = fmaf(ip[p],          mv, nr);
        ng  = fmaf(ip[HW + p],     mv, ng);
        nb  = fmaf(ip[2 * HW + p], mv, nb);
    }
#pragma unroll
    for (int off = 32; off >= 1; off >>= 1) {
        d  += __shfl_down(d,  off);
        nr += __shfl_down(nr, off);
        ng += __shfl_down(ng, off);
        nb += __shfl_down(nb, off);
    }
    __shared__ float sred[4][4];
    const int wave = threadIdx.x >> 6;
    const int lane = threadIdx.x & 63;
    if (lane == 0) {
        sred[wave][0] = d; sred[wave][1] = nr; sred[wave][2] = ng; sred[wave][3] = nb;
    }
    __syncthreads();
    if (threadIdx.x == 0) {
        float D  = sred[0][0] + sred[1][0] + sred[2][0] + sred[3][0];
        float R  = sred[0][1] + sred[1][1] + sred[2][1] + sred[3][1];
        float G  = sred[0][2] + sred[1][2] + sred[2][2] + sred[3][2];
        float Bv = sred[0][3] + sred[1][3] + sred[2][3] + sred[3][3];
        den_ws[b * K + k] = D;
        num_ws[(b * 3 + 0) * K + k] = R;
        num_ws[(b * 3 + 1) * K + k] = G;
        num_ws[(b * 3 + 2) * K + k] = Bv;
    }
}

// Kernel P: palette[b,c,k] = num/(den+eps)
__global__ __launch_bounds__(256) void colorcnn_palette(
    const float* __restrict__ den_ws, const float* __restrict__ num_ws,
    float* __restrict__ pal_out)
{
    const int i = blockIdx.x * 256 + threadIdx.x;
    if (i >= BATCH * K) return;
    const int b = i >> 6;
    const int k = i & 63;
    const float dv = den_ws[i] + 1e-8f;
#pragma unroll
    for (int c = 0; c < 3; ++c)
        pal_out[b * 3 * K + c * K + k] = num_ws[(b * 3 + c) * K + k] / dv;
}

// Kernel C: transformed[b,c,p] = sum_k m[b,k,p] * palette[b,c,k]
__global__ __launch_bounds__(256) void colorcnn_reconstruct(
    const float* __restrict__ m, const float* __restrict__ pal,
    float* __restrict__ t_out)
{
    const int b = blockIdx.x / REC_BLOCKS_PER_IMG;
    const int p = (blockIdx.x % REC_BLOCKS_PER_IMG) * 256 + threadIdx.x;

    const float* mp = m + (size_t)b * K * HW + p;
    const float* pb = pal + b * 3 * K;

    float ar = 0.f, ag = 0.f, ab = 0.f;
#pragma unroll
    for (int k = 0; k < K; ++k) {
        const float mv = mp[(size_t)k * HW];
        ar = fmaf(mv, pb[k],         ar);
        ag = fmaf(mv, pb[K + k],     ag);
        ab = fmaf(mv, pb[2 * K + k], ab);
    }
    float* to = t_out + (size_t)b * 3 * HW + p;
    to[0]      = ar;
    to[HW]     = ag;
    to[2 * HW] = ab;
}

extern "C" void kernel_launch(void* const* d_in, const int* in_sizes, int n_in,
                              void* d_out, int out_size, void* d_ws, size_t ws_size,
                              hipStream_t stream) {
    const float* img = (const float*)d_in[0];
    const float* W1  = (const float*)d_in[1];
    const float* b1  = (const float*)d_in[2];
    const float* W2  = (const float*)d_in[3];

    float* out   = (float*)d_out;
    float* t_out = out + OUT_T_OFF;
    float* m_out = out + OUT_M_OFF;
    float* p_out = out + OUT_P_OFF;

    float*  wsf    = (float*)d_ws;
    float*  den_ws = wsf + WS_DEN;
    float*  num_ws = wsf + WS_NUM;
    float4* w1p    = (float4*)(wsf + WS_W1P);
    ushort* w2b    = (ushort*)(wsf + WS_W2B);

    colorcnn_prep<<<1, 256, 0, stream>>>(W1, b1, W2, w1p, w2b);
    colorcnn_mlp_softmax<<<dim3(HW / 128, BATCH), 256, 0, stream>>>(img, w1p, w2b, m_out);
    colorcnn_reduce<<<BATCH * K, 256, 0, stream>>>(img, m_out, den_ws, num_ws);
    colorcnn_palette<<<4, 256, 0, stream>>>(den_ws, num_ws, p_out);
    colorcnn_reconstruct<<<BATCH * REC_BLOCKS_PER_IMG, 256, 0, stream>>>(m_out, p_out, t_out);
}

// Round 5
// 132.823 us; speedup vs baseline: 9.4823x; 1.4069x over previous
//
#include <hip/hip_runtime.h>
#include <hip/hip_bf16.h>

#define BATCH 16
#define HW 50176          // 224*224
#define HID 256
#define K 64

// output layout (floats): transformed [0, 2408448) | m [2408448, 53788672) | palette [53788672, +3072)
#define OUT_T_OFF 0
#define OUT_M_OFF 2408448
#define OUT_P_OFF 53788672

// workspace layout (floats): den [0,1024) | num [1024,4096) | w1p float4 [4096,5120) | w2b bf16 @ float-offset 5120 (32KB)
#define WS_DEN 0
#define WS_NUM 1024
#define WS_W1P 4096
#define WS_W2B 5120

typedef short bf16x8 __attribute__((ext_vector_type(8)));
typedef float f32x4  __attribute__((ext_vector_type(4)));

static __device__ __forceinline__ short f2bf(float x) {
    union { __hip_bfloat16 h; short s; } u;
    u.h = __float2bfloat16(x);
    return u.s;
}

// Prep: zero den/num accumulators; pack W1+b1 into float4[256]; convert W2 to bf16[64*256].
__global__ __launch_bounds__(256) void colorcnn_prep(
    const float* __restrict__ W1, const float* __restrict__ b1,
    const float* __restrict__ W2, float* __restrict__ wsf,
    float4* __restrict__ w1p, ushort* __restrict__ w2b)
{
    const int t = threadIdx.x;
#pragma unroll
    for (int q = 0; q < 16; ++q) wsf[q * 256 + t] = 0.f;   // den[1024] + num[3072]
    w1p[t] = make_float4(W1[3 * t], W1[3 * t + 1], W1[3 * t + 2], b1[t]);
#pragma unroll
    for (int q = 0; q < 64; ++q) {
        const int i = q * 256 + t;
        w2b[i] = (ushort)f2bf(W2[i]);
    }
}

// Kernel A: per-pixel MLP via MFMA + softmax, write m, and fused den/num reduction.
// Block = 128 consecutive pixels of image blockIdx.y; 4 waves x 32 px each.
__global__ __launch_bounds__(256) void colorcnn_mlp_softmax(
    const float* __restrict__ img, const float4* __restrict__ w1p,
    const ushort* __restrict__ w2b, float* __restrict__ m_out,
    float* __restrict__ den_ws, float* __restrict__ num_ws)
{
    __shared__ int4 lds[2304];       // [0,2048): w2b swizzled; [2048,2304): w1p swizzled
    __shared__ float sred[4][256];   // per-wave den/num partials

    const int t = threadIdx.x;
    // stage w2b: 2048 16B units; unit s of row n stored at n*32 + (s ^ (n&7))
    const int4* w2b16 = (const int4*)w2b;
#pragma unroll
    for (int q = 0; q < 8; ++q) {
        const int i = t + q * 256;
        const int n = i >> 5, s = i & 31;
        lds[n * 32 + (s ^ (n & 7))] = w2b16[i];
    }
    // stage w1p: unit hid stored at 2048 + (hid ^ ((hid>>3)&3))
    lds[2048 + (t ^ ((t >> 3) & 3))] = ((const int4*)w1p)[t];
    __syncthreads();

    const int b    = blockIdx.y;
    const int pb   = blockIdx.x * 128;
    const int w    = t >> 6;
    const int lane = t & 63;
    const int l15  = lane & 15;
    const int lg   = lane >> 4;

    const float* ip = img + (size_t)b * 3 * HW;
    const int px0 = pb + w * 32 + l15;
    const int px1 = px0 + 16;
    const float r0 = ip[px0], g0 = ip[HW + px0], u0 = ip[2 * HW + px0];
    const float r1 = ip[px1], g1 = ip[HW + px1], u1 = ip[2 * HW + px1];

    f32x4 acc[2][4];
#pragma unroll
    for (int mi = 0; mi < 2; ++mi)
#pragma unroll
        for (int ni = 0; ni < 4; ++ni)
            acc[mi][ni] = (f32x4){0.f, 0.f, 0.f, 0.f};

#pragma unroll
    for (int c = 0; c < 8; ++c) {
        // Build A fragments: lane holds h[px][hid], hid = c*32 + lg*8 + j
        bf16x8 a0, a1;
#pragma unroll
        for (int j = 0; j < 8; ++j) {
            const int hid = c * 32 + lg * 8 + j;
            const float4 wv = *(const float4*)&lds[2048 + (hid ^ lg)];
            float t0 = fmaf(r0, wv.x, fmaf(g0, wv.y, fmaf(u0, wv.z, wv.w)));
            float t1 = fmaf(r1, wv.x, fmaf(g1, wv.y, fmaf(u1, wv.z, wv.w)));
            a0[j] = f2bf(fmaxf(t0, 0.f));
            a1[j] = f2bf(fmaxf(t1, 0.f));
        }
        // B fragments from LDS (swizzled) + 8 MFMA
#pragma unroll
        for (int ni = 0; ni < 4; ++ni) {
            const int n = ni * 16 + l15;
            const bf16x8 bf = *(const bf16x8*)&lds[n * 32 + (((c * 4 + lg) ^ (n & 7)))];
            acc[0][ni] = __builtin_amdgcn_mfma_f32_16x16x32_bf16(a0, bf, acc[0][ni], 0, 0, 0);
            acc[1][ni] = __builtin_amdgcn_mfma_f32_16x16x32_bf16(a1, bf, acc[1][ni], 0, 0, 0);
        }
    }

    // Softmax over n (64 outputs) per pixel. C layout: col(n)=ni*16+l15, row(px)=mi*16+lg*4+reg.
    // Rows are identical across the 16 lanes sharing lg -> reduce over l15 via shfl_xor 1,2,4,8.
#pragma unroll
    for (int mi = 0; mi < 2; ++mi) {
#pragma unroll
        for (int reg = 0; reg < 4; ++reg) {
            float v0 = acc[mi][0][reg], v1 = acc[mi][1][reg];
            float v2 = acc[mi][2][reg], v3 = acc[mi][3][reg];
            float mx = fmaxf(fmaxf(v0, v1), fmaxf(v2, v3));
            mx = fmaxf(mx, __shfl_xor(mx, 1));
            mx = fmaxf(mx, __shfl_xor(mx, 2));
            mx = fmaxf(mx, __shfl_xor(mx, 4));
            mx = fmaxf(mx, __shfl_xor(mx, 8));
            v0 = __expf(v0 - mx); v1 = __expf(v1 - mx);
            v2 = __expf(v2 - mx); v3 = __expf(v3 - mx);
            float s = (v0 + v1) + (v2 + v3);
            s += __shfl_xor(s, 1);
            s += __shfl_xor(s, 2);
            s += __shfl_xor(s, 4);
            s += __shfl_xor(s, 8);
            const float inv = 1.f / s;
            acc[mi][0][reg] = v0 * inv; acc[mi][1][reg] = v1 * inv;
            acc[mi][2][reg] = v2 * inv; acc[mi][3][reg] = v3 * inv;
        }
    }

    // Store m: per (mi,ni) the 4 regs are 4 consecutive px -> dwordx4; 16 full 64B lines per instr.
    float* mo = m_out + (size_t)b * K * HW + pb + w * 32;
#pragma unroll
    for (int mi = 0; mi < 2; ++mi)
#pragma unroll
        for (int ni = 0; ni < 4; ++ni) {
            const int n = ni * 16 + l15;
            *(f32x4*)&mo[(size_t)n * HW + mi * 16 + lg * 4] = acc[mi][ni];
        }

    // ---- Fused den/num reduction (saves kernel B's 215 MB re-read) ----
    // Lane's pixels in C layout: px = pb + w*32 + mi*16 + lg*4 + reg. Broadcast f32x4 img loads.
    f32x4 rC[2], gC[2], uC[2];
#pragma unroll
    for (int mi = 0; mi < 2; ++mi) {
        const int pxb = pb + w * 32 + mi * 16 + lg * 4;
        rC[mi] = *(const f32x4*)&ip[pxb];
        gC[mi] = *(const f32x4*)&ip[HW + pxb];
        uC[mi] = *(const f32x4*)&ip[2 * HW + pxb];
    }
    float red[16];   // [q*4+ni], q: 0=den 1=numR 2=numG 3=numB
#pragma unroll
    for (int ni = 0; ni < 4; ++ni) {
        float d = 0.f, nr = 0.f, ng = 0.f, nb = 0.f;
#pragma unroll
        for (int mi = 0; mi < 2; ++mi) {
#pragma unroll
            for (int reg = 0; reg < 4; ++reg) {
                const float mv = acc[mi][ni][reg];
                d += mv;
                nr = fmaf(rC[mi][reg], mv, nr);
                ng = fmaf(gC[mi][reg], mv, ng);
                nb = fmaf(uC[mi][reg], mv, nb);
            }
        }
        red[ni] = d; red[4 + ni] = nr; red[8 + ni] = ng; red[12 + ni] = nb;
    }
    // Reduce across the 4 lane-groups (lanes sharing l15): xor 16, 32.
#pragma unroll
    for (int i = 0; i < 16; ++i) {
        red[i] += __shfl_xor(red[i], 16);
        red[i] += __shfl_xor(red[i], 32);
    }
    if (lg == 0) {
#pragma unroll
        for (int ni = 0; ni < 4; ++ni) {
            const int n = ni * 16 + l15;
            sred[w][n]       = red[ni];
            sred[w][64 + n]  = red[4 + ni];
            sred[w][128 + n] = red[8 + ni];
            sred[w][192 + n] = red[12 + ni];
        }
    }
    __syncthreads();
    {
        const int q = t >> 6, n = t & 63;
        const float v = sred[0][t] + sred[1][t] + sred[2][t] + sred[3][t];
        if (q == 0) atomicAdd(&den_ws[b * K + n], v);
        else        atomicAdd(&num_ws[(b * 3 + (q - 1)) * K + n], v);
    }
}

// Kernel P: palette[b,c,k] = num/(den+eps)
__global__ __launch_bounds__(256) void colorcnn_palette(
    const float* __restrict__ den_ws, const float* __restrict__ num_ws,
    float* __restrict__ pal_out)
{
    const int i = blockIdx.x * 256 + threadIdx.x;
    if (i >= BATCH * K) return;
    const int b = i >> 6;
    const int k = i & 63;
    const float dv = den_ws[i] + 1e-8f;
#pragma unroll
    for (int c = 0; c < 3; ++c)
        pal_out[b * 3 * K + c * K + k] = num_ws[(b * 3 + c) * K + k] / dv;
}

// Kernel C: transformed[b,c,p] = sum_k m[b,k,p] * palette[b,c,k]. 4 px/thread, f32x4.
__global__ __launch_bounds__(256) void colorcnn_reconstruct(
    const float* __restrict__ m, const float* __restrict__ pal,
    float* __restrict__ t_out)
{
    __shared__ float pl[192];
    const int b = blockIdx.x / 49;
    const int p = (blockIdx.x % 49) * 1024 + threadIdx.x * 4;

    if (threadIdx.x < 192) pl[threadIdx.x] = pal[b * 3 * K + threadIdx.x];
    __syncthreads();

    const float* mp = m + (size_t)b * K * HW + p;
    f32x4 ar = {0.f, 0.f, 0.f, 0.f}, ag = ar, ab = ar;
#pragma unroll
    for (int k = 0; k < K; ++k) {
        const f32x4 mv = *(const f32x4*)&mp[(size_t)k * HW];
        const float pr = pl[k], pg = pl[K + k], pu = pl[2 * K + k];
#pragma unroll
        for (int j = 0; j < 4; ++j) {
            ar[j] = fmaf(mv[j], pr, ar[j]);
            ag[j] = fmaf(mv[j], pg, ag[j]);
            ab[j] = fmaf(mv[j], pu, ab[j]);
        }
    }
    float* to = t_out + (size_t)b * 3 * HW + p;
    *(f32x4*)&to[0]      = ar;
    *(f32x4*)&to[HW]     = ag;
    *(f32x4*)&to[2 * HW] = ab;
}

extern "C" void kernel_launch(void* const* d_in, const int* in_sizes, int n_in,
                              void* d_out, int out_size, void* d_ws, size_t ws_size,
                              hipStream_t stream) {
    const float* img = (const float*)d_in[0];
    const float* W1  = (const float*)d_in[1];
    const float* b1  = (const float*)d_in[2];
    const float* W2  = (const float*)d_in[3];

    float* out   = (float*)d_out;
    float* t_out = out + OUT_T_OFF;
    float* m_out = out + OUT_M_OFF;
    float* p_out = out + OUT_P_OFF;

    float*  wsf    = (float*)d_ws;
    float*  den_ws = wsf + WS_DEN;
    float*  num_ws = wsf + WS_NUM;
    float4* w1p    = (float4*)(wsf + WS_W1P);
    ushort* w2b    = (ushort*)(wsf + WS_W2B);

    colorcnn_prep<<<1, 256, 0, stream>>>(W1, b1, W2, wsf, w1p, w2b);
    colorcnn_mlp_softmax<<<dim3(HW / 128, BATCH), 256, 0, stream>>>(img, w1p, w2b, m_out, den_ws, num_ws);
    colorcnn_palette<<<4, 256, 0, stream>>>(den_ws, num_ws, p_out);
    colorcnn_reconstruct<<<BATCH * 49, 256, 0, stream>>>(m_out, p_out, t_out);
}